// Round 8
// baseline (293.302 us; speedup 1.0000x reference)
//
#include <hip/hip_runtime.h>
#include <hip/hip_bf16.h>

typedef __bf16 bf16;
typedef __bf16 bf16x8 __attribute__((ext_vector_type(8)));
typedef float floatx4 __attribute__((ext_vector_type(4)));

// B=2, T=512, C=8, D=512, H=8, dk=64. M = B*T*C = 8192.
// Inputs fp32 (dict order), output fp32.
// ws regions (R = 8192*512*2 B = 8.39 MB):
//   r0 r1 r2 r3 | WT (4 x 512x512 bf16 = 2 MB)   peak 35.7 MB
// Alias chain (stream-ordered): cvt q,k,v -> r0,r1,r2 ; wtr -> WT ;
// gemmV r2->r3 ; gemmK r1->r2 ; gemmQ r0->r1 ; attn (r1,r2,r3)->r0 ;
// out r0 -> d_out.   Q,K: [hd][t][d]; V^T: [hd][d][t]; hd = b*64+h*8+c.

union Pack8 { bf16 h[8]; uint4 u; };

// ---------------- fp32 -> bf16 bulk convert: grid (2048, 3) x 256 ------------
__global__ __launch_bounds__(256) void cvt_kernel(
    const float* __restrict__ q, const float* __restrict__ k,
    const float* __restrict__ v,
    bf16* __restrict__ qa, bf16* __restrict__ ka, bf16* __restrict__ va)
{
    const float* src; bf16* dst;
    if (blockIdx.y == 0)      { src = q; dst = qa; }
    else if (blockIdx.y == 1) { src = k; dst = ka; }
    else                      { src = v; dst = va; }
    const size_t i = ((size_t)blockIdx.x * 256 + threadIdx.x) * 8;
    float4 a = *(const float4*)(src + i);
    float4 b = *(const float4*)(src + i + 4);
    Pack8 r;
    r.h[0] = (bf16)a.x; r.h[1] = (bf16)a.y; r.h[2] = (bf16)a.z; r.h[3] = (bf16)a.w;
    r.h[4] = (bf16)b.x; r.h[5] = (bf16)b.y; r.h[6] = (bf16)b.z; r.h[7] = (bf16)b.w;
    *(uint4*)(dst + i) = r.u;
}

// ---------------- weight transpose W[K][N] fp32 -> WT[N][K] bf16 -------------
// grid (8, 8, 4) x 256 ; 64x64 tiles through LDS.
__global__ __launch_bounds__(256) void wtr_kernel(
    const float* __restrict__ Wq, const float* __restrict__ Wk,
    const float* __restrict__ Wv, const float* __restrict__ Wo,
    bf16* __restrict__ WT)
{
    __shared__ float Ts[64][65];
    const int tid = threadIdx.x;
    const int k0 = blockIdx.x * 64;
    const int n0 = blockIdx.y * 64;
    const int z  = blockIdx.z;
    const float* W = (z == 0) ? Wq : (z == 1) ? Wk : (z == 2) ? Wv : Wo;
    bf16* O = WT + (size_t)z * 512 * 512;
    #pragma unroll
    for (int i = 0; i < 16; i++) {
        const int r = i * 4 + (tid >> 6), c = tid & 63;
        Ts[r][c] = W[(size_t)(k0 + r) * 512 + n0 + c];
    }
    __syncthreads();
    #pragma unroll
    for (int i = 0; i < 16; i++) {
        const int a = i * 4 + (tid >> 6), b = tid & 63;
        O[(size_t)(n0 + a) * 512 + k0 + b] = (bf16)Ts[b][a];
    }
}

// ---------------- LDS-free GEMM: C[M=8192][512] = A[M][512] @ WT^T + bias ----
// A and BT both K-major bf16. Block 256 = 4 waves covering 64x128;
// wave-tile 32x64 (acc[2][4]); per K-step: 6 global b128 loads + 8 MFMA.
// LAYOUT 0: bf16 [hd][t][d]; 1: bf16 [hd][d][t]; 2: fp32 row-major.
template<int LAYOUT, typename TO>
__global__ __launch_bounds__(256) void gemm_nl(
    const bf16* __restrict__ A, const bf16* __restrict__ BT,
    const float* __restrict__ bias, TO* __restrict__ out)
{
    const int tid  = threadIdx.x;
    const int lane = tid & 63;
    const int wave = tid >> 6;
    const int quad = lane >> 4;
    const int l16  = lane & 15;
    const int mblk = blockIdx.x * 64;
    const int nblk = blockIdx.y * 128;
    const int wr = (wave >> 1) * 32;
    const int wc = (wave & 1) * 64;

    const bf16* Ap = A  + (size_t)(mblk + wr + l16) * 512 + quad * 8;
    const bf16* Bp = BT + (size_t)(nblk + wc + l16) * 512 + quad * 8;

    floatx4 acc[2][4] = {};
    for (int k0 = 0; k0 < 512; k0 += 32) {
        bf16x8 a[2], b[4];
        #pragma unroll
        for (int mt = 0; mt < 2; mt++)
            a[mt] = *(const bf16x8*)(Ap + (size_t)mt * 16 * 512 + k0);
        #pragma unroll
        for (int nt = 0; nt < 4; nt++)
            b[nt] = *(const bf16x8*)(Bp + (size_t)nt * 16 * 512 + k0);
        #pragma unroll
        for (int mt = 0; mt < 2; mt++)
            #pragma unroll
            for (int nt = 0; nt < 4; nt++)
                acc[mt][nt] = __builtin_amdgcn_mfma_f32_16x16x32_bf16(
                    a[mt], b[nt], acc[mt][nt], 0, 0, 0);
    }

    #pragma unroll
    for (int mt = 0; mt < 2; mt++) {
        #pragma unroll
        for (int nt = 0; nt < 4; nt++) {
            const int colg = nblk + wc + nt * 16 + l16;
            const float bb = bias[colg];
            #pragma unroll
            for (int r = 0; r < 4; r++) {
                const int rowg = mblk + wr + mt * 16 + quad * 4 + r;
                float v = acc[mt][nt][r] + bb;
                size_t addr;
                if (LAYOUT == 2) {
                    addr = (size_t)rowg * 512 + colg;
                } else {
                    const int b = rowg >> 12;
                    const int t = (rowg >> 3) & 511;
                    const int c = rowg & 7;
                    const int h = colg >> 6;
                    const int d = colg & 63;
                    const int hd = b * 64 + h * 8 + c;
                    if (LAYOUT == 0) addr = ((size_t)hd * 512 + t) * 64 + d;
                    else             addr = ((size_t)hd * 64 + d) * 512 + t;
                }
                out[addr] = (TO)v;
            }
        }
    }
}

// ---------------- attention: one block = one head x 16 queries ---------------
#define SST 520
#define PST 520

__global__ __launch_bounds__(256) void attn_kernel(
    const bf16* __restrict__ Qws, const bf16* __restrict__ Kws,
    const bf16* __restrict__ Vtws, const int* __restrict__ mask,
    bf16* __restrict__ Xws)
{
    __shared__ float Ssm[16][SST];
    __shared__ bf16  Psm[16][PST];
    const int tid  = threadIdx.x;
    const int wave = tid >> 6;
    const int lane = tid & 63;
    const int quad = lane >> 4;
    const int l16  = lane & 15;
    const int qt = blockIdx.x;
    const int hd = blockIdx.y;
    const int q0 = qt * 16;
    const int b = hd >> 6;
    const int h = (hd >> 3) & 7;
    const int c = hd & 7;

    const bf16* Qh = Qws + (size_t)hd * 512 * 64;
    const bf16* Kh = Kws + (size_t)hd * 512 * 64;
    bf16x8 aq0 = *(const bf16x8*)(Qh + (size_t)(q0 + l16) * 64 + quad * 8);
    bf16x8 aq1 = *(const bf16x8*)(Qh + (size_t)(q0 + l16) * 64 + 32 + quad * 8);
    #pragma unroll
    for (int nt = 0; nt < 8; nt++) {
        const int s0 = wave * 128 + nt * 16;
        bf16x8 bk0 = *(const bf16x8*)(Kh + (size_t)(s0 + l16) * 64 + quad * 8);
        bf16x8 bk1 = *(const bf16x8*)(Kh + (size_t)(s0 + l16) * 64 + 32 + quad * 8);
        floatx4 s = {};
        s = __builtin_amdgcn_mfma_f32_16x16x32_bf16(aq0, bk0, s, 0, 0, 0);
        s = __builtin_amdgcn_mfma_f32_16x16x32_bf16(aq1, bk1, s, 0, 0, 0);
        #pragma unroll
        for (int r = 0; r < 4; r++)
            Ssm[quad * 4 + r][s0 + l16] = s[r] * 0.125f;
    }
    __syncthreads();

    {
        const int row = tid >> 4;
        const int i0  = tid & 15;
        const int t   = q0 + row;
        const int* mrow = mask + ((size_t)b * 512 + t) * 512;
        float sv[32];
        float mx = -3.0e38f;
        #pragma unroll
        for (int jj = 0; jj < 32; jj++) {
            const int col = i0 + 16 * jj;
            float s = Ssm[row][col];
            if (mrow[col] == 0) s = -1.0e9f;
            sv[jj] = s;
            mx = fmaxf(mx, s);
        }
        #pragma unroll
        for (int off = 1; off < 16; off <<= 1) mx = fmaxf(mx, __shfl_xor(mx, off, 64));
        float sum = 0.f;
        #pragma unroll
        for (int jj = 0; jj < 32; jj++) { float e = __expf(sv[jj] - mx); sv[jj] = e; sum += e; }
        #pragma unroll
        for (int off = 1; off < 16; off <<= 1) sum += __shfl_xor(sum, off, 64);
        const float inv = 1.f / sum;
        #pragma unroll
        for (int jj = 0; jj < 32; jj++)
            Psm[row][i0 + 16 * jj] = (bf16)(sv[jj] * inv);
    }
    __syncthreads();

    const bf16* Vh = Vtws + (size_t)hd * 64 * 512;
    const int d0 = wave * 16;
    floatx4 o = {};
    #pragma unroll
    for (int ks = 0; ks < 16; ks++) {
        bf16x8 ap = *(const bf16x8*)(&Psm[l16][ks * 32 + quad * 8]);
        bf16x8 bv = *(const bf16x8*)(Vh + (size_t)(d0 + l16) * 512 + ks * 32 + quad * 8);
        o = __builtin_amdgcn_mfma_f32_16x16x32_bf16(ap, bv, o, 0, 0, 0);
    }
    #pragma unroll
    for (int r = 0; r < 4; r++) {
        const int q = quad * 4 + r;
        const size_t row = ((size_t)b * 512 + q0 + q) * 8 + c;
        Xws[row * 512 + h * 64 + d0 + l16] = (bf16)o[r];
    }
}

extern "C" void kernel_launch(void* const* d_in, const int* in_sizes, int n_in,
                              void* d_out, int out_size, void* d_ws, size_t ws_size,
                              hipStream_t stream)
{
    const float* qin  = (const float*)d_in[0];
    const float* kin  = (const float*)d_in[1];
    const float* vin  = (const float*)d_in[2];
    const int*   mask = (const int*)d_in[3];
    const float* Bq = (const float*)d_in[5];
    const float* Bk = (const float*)d_in[7];
    const float* Bv = (const float*)d_in[9];
    const float* Bo = (const float*)d_in[11];
    float* out = (float*)d_out;

    const size_t R = (size_t)8192 * 512;   // elements per region
    bf16* r0 = (bf16*)d_ws;
    bf16* r1 = r0 + R;
    bf16* r2 = r1 + R;
    bf16* r3 = r2 + R;
    bf16* WT = r3 + R;                      // 4 x 262144 bf16

    // 1. convert q,k,v fp32 -> bf16
    cvt_kernel<<<dim3(2048, 3), dim3(256), 0, stream>>>(
        qin, kin, vin, r0, r1, r2);
    // 2. transpose+convert weights -> WT[N][K]
    wtr_kernel<<<dim3(8, 8, 4), dim3(256), 0, stream>>>(
        (const float*)d_in[4], (const float*)d_in[6],
        (const float*)d_in[8], (const float*)d_in[10], WT);
    // 3. V projection: Va(r2) -> V^T (r3)
    gemm_nl<1, bf16><<<dim3(128, 4), dim3(256), 0, stream>>>(
        r2, WT + 2 * 262144, Bv, r3);
    // 4. K projection: Ka(r1) -> K (r2)
    gemm_nl<0, bf16><<<dim3(128, 4), dim3(256), 0, stream>>>(
        r1, WT + 1 * 262144, Bk, r2);
    // 5. Q projection: Qa(r0) -> Q (r1)
    gemm_nl<0, bf16><<<dim3(128, 4), dim3(256), 0, stream>>>(
        r0, WT + 0 * 262144, Bq, r1);
    // 6. attention -> X (r0)
    attn_kernel<<<dim3(32, 128), dim3(256), 0, stream>>>(
        r1, r2, r3, mask, r0);
    // 7. output projection: X(r0) @ Wo + bo -> out (fp32)
    gemm_nl<2, float><<<dim3(128, 4), dim3(256), 0, stream>>>(
        r0, WT + 3 * 262144, Bo, out);
}